// Round 15
// baseline (878.864 us; speedup 1.0000x reference)
//
#include <hip/hip_runtime.h>

// ---------------------------------------------------------------------------
// GIN forward on MI355X.
//   prep_w1_all (all L layers W1 -> transposed bf16 hi/lo + zero all stats)
//   CSR build (zero, hist, scan x3, fill)
//   per layer: fused_agg_gemm1 (512 thr, 64-node tile, 4 blocks/CU: gather ->
//              LDS bf16 hi/lo; 8 waves split-bf16 MFMA + bias+leaky+stats)
//              w2t_fold (BN fold + W2 transform + b2')
//              gemm2_split (512 thr, LDS-staged A, split-bf16 MFMA -> fp32)
//   pool (block-per-graph, binary-search bounds), pool_stats, final_fc
// ---------------------------------------------------------------------------

typedef __attribute__((ext_vector_type(8))) __bf16 bf16x8;
typedef __attribute__((ext_vector_type(4))) float  f32x4;

__device__ __forceinline__ unsigned short f2bf(float f) {
    union { float f; unsigned int u; } v; v.f = f;
    unsigned int r = v.u + 0x7fffu + ((v.u >> 16) & 1u);
    return (unsigned short)(r >> 16);
}
__device__ __forceinline__ float bf2f(unsigned short h) {
    union { unsigned int u; float f; } v; v.u = ((unsigned int)h) << 16;
    return v.f;
}

// ------------------------------ CSR build ---------------------------------

__global__ void zero2_kernel(int* __restrict__ a, int* __restrict__ b, int n) {
    int i = blockIdx.x * 256 + threadIdx.x;
    if (i < n) { a[i] = 0; b[i] = 0; }
}

__global__ void hist_kernel(const int* __restrict__ dst, int* __restrict__ deg, int E) {
    int e = blockIdx.x * 256 + threadIdx.x;
    if (e < E) atomicAdd(&deg[dst[e]], 1);
}

__global__ void scan1_kernel(const int* __restrict__ deg, int* __restrict__ ofs,
                             int* __restrict__ bsum, int n) {
    __shared__ int sh[256];
    int tid = threadIdx.x;
    int i = blockIdx.x * 256 + tid;
    int v = (i < n) ? deg[i] : 0;
    sh[tid] = v;
    __syncthreads();
    for (int o = 1; o < 256; o <<= 1) {
        int tmp = (tid >= o) ? sh[tid - o] : 0;
        __syncthreads();
        sh[tid] += tmp;
        __syncthreads();
    }
    if (i < n) ofs[i] = sh[tid] - v;           // exclusive within block
    if (tid == 255) bsum[blockIdx.x] = sh[255];
}

__global__ void scan2_kernel(int* __restrict__ bsum, int nb) {
    __shared__ int sh[1024];
    int tid = threadIdx.x;
    int v = (tid < nb) ? bsum[tid] : 0;
    sh[tid] = v;
    __syncthreads();
    for (int o = 1; o < 1024; o <<= 1) {
        int tmp = (tid >= o) ? sh[tid - o] : 0;
        __syncthreads();
        sh[tid] += tmp;
        __syncthreads();
    }
    if (tid < nb) bsum[tid] = sh[tid] - v;     // exclusive
}

__global__ void scan3_kernel(int* __restrict__ ofs, const int* __restrict__ bsum,
                             int n, int Etot) {
    int i = blockIdx.x * 256 + threadIdx.x;
    if (i < n) ofs[i] += bsum[blockIdx.x];
    if (i == 0) ofs[n] = Etot;
}

__global__ void fill_kernel(const int* __restrict__ src, const int* __restrict__ dst,
                            const int* __restrict__ ofs, int* __restrict__ cur,
                            int* __restrict__ csr, int E) {
    int e = blockIdx.x * 256 + threadIdx.x;
    if (e >= E) return;
    int d = dst[e];
    int p = atomicAdd(&cur[d], 1);
    csr[ofs[d] + p] = src[e];
}

// --------------------------- weight prep ----------------------------------
// All L layers at once: W1s[l][k][n] fp32 -> Bt[l][n][k] bf16 hi/lo.
// Also zeroes all layers' column stats (re-poisoned each call).

__global__ void prep_w1_all(const float* __restrict__ W1s, unsigned short* __restrict__ Bth,
                            unsigned short* __restrict__ Btl,
                            float* __restrict__ colsum, float* __restrict__ colsq,
                            int total, int nstats) {
    int t = blockIdx.x * 256 + threadIdx.x;   // total = L*16384
    if (t < nstats) { colsum[t] = 0.f; colsq[t] = 0.f; }
    if (t >= total) return;
    int lbase = t & ~16383;                   // layer offset
    int r = t & 16383;
    int n = r >> 7, k = r & 127;
    float v = W1s[lbase + k * 128 + n];
    unsigned short h = f2bf(v);
    Bth[t] = h;
    Btl[t] = f2bf(v - bf2f(h));
}

// BN fold + W2 transform + b2' in one kernel (64 blocks).
__global__ void w2t_fold(const float* __restrict__ W2, const float* __restrict__ b2,
                         const float* __restrict__ g1, const float* __restrict__ be1,
                         const float* __restrict__ colsum, const float* __restrict__ colsq,
                         unsigned short* __restrict__ Bth, unsigned short* __restrict__ Btl,
                         float* __restrict__ b2p, int nrows) {
    __shared__ float s[128], tt[128];
    int tid = threadIdx.x;          // 256 threads
    if (tid < 128) {
        float mu = colsum[tid] / (float)nrows;
        float var = colsq[tid] / (float)nrows - mu * mu;
        float rs = rsqrtf(var + 1e-5f);
        float sc = rs * g1[tid];
        s[tid] = sc;
        tt[tid] = be1[tid] - mu * sc;
    }
    __syncthreads();
    int t = blockIdx.x * 256 + tid;           // 64 blocks * 256 = 16384
    int n = t >> 7, k = t & 127;
    float v = s[k] * W2[k * 128 + n];
    unsigned short h = f2bf(v);
    Bth[t] = h;
    Btl[t] = f2bf(v - bf2f(h));
    if (blockIdx.x == 0) {
        __shared__ float part[2][128];
        int nn = tid & 127, half = tid >> 7;
        float acc = 0.f;
        for (int kk = half * 64; kk < half * 64 + 64; ++kk)
            acc += tt[kk] * W2[kk * 128 + nn];
        part[half][nn] = acc;
        __syncthreads();
        if (tid < 128) b2p[tid] = b2[tid] + part[0][tid] + part[1][tid];
    }
}

// --------------------- fused aggregation + GEMM-1 --------------------------
// 512 threads, 64-node tile, 34.8 KB LDS; __launch_bounds__(512,8) -> VGPR<=64
// (measured 32), 4 blocks/CU = 32 waves/CU.
// Phase A: 16 half-waves gather 4 nodes each (float4 rows, 8-deep pipeline).
// Phase B: 8 waves, one 16-col group each over 64 rows; split-bf16 MFMA;
//          bias + leaky; write h1 hi/lo + column stats.

#define APAD 136   // 128 + 8 bf16 pad: row stride 272B, 16B-aligned, 2-way banks

__launch_bounds__(512, 8)
__global__ void fused_agg_gemm1(const float* __restrict__ h, const int* __restrict__ ofs,
                                const int* __restrict__ csr,
                                const unsigned short* __restrict__ Bh,
                                const unsigned short* __restrict__ Bl,
                                const float* __restrict__ bias,
                                unsigned short* __restrict__ Ohi,
                                unsigned short* __restrict__ Olo,
                                float* __restrict__ colsum, float* __restrict__ colsq,
                                int n) {
    __shared__ unsigned short AhL[64][APAD];
    __shared__ unsigned short AlL[64][APAD];

    const int rowbase = blockIdx.x * 64;
    const int hw = threadIdx.x >> 5;       // half-wave 0..15
    const int lane = threadIdx.x & 31;
    const float4* base = (const float4*)h;

    // ---- Phase A: gather 4 nodes per half-wave ----
    for (int i = 0; i < 4; ++i) {
        int lrow = hw * 4 + i;
        int node = rowbase + lrow;
        float ax = 0.f, ay = 0.f, az = 0.f, aw = 0.f;
        if (node < n) {
            float4 a = base[node * 32 + lane];
            ax = a.x; ay = a.y; az = a.z; aw = a.w;
            int e0 = ofs[node], e1 = ofs[node + 1];
            int j = e0;
            for (; j + 8 <= e1; j += 8) {
                int s[8];
#pragma unroll
                for (int u = 0; u < 8; ++u) s[u] = csr[j + u];
                float4 v[8];
#pragma unroll
                for (int u = 0; u < 8; ++u) v[u] = base[s[u] * 32 + lane];
#pragma unroll
                for (int u = 0; u < 8; ++u) {
                    ax += v[u].x; ay += v[u].y; az += v[u].z; aw += v[u].w;
                }
            }
            for (; j + 4 <= e1; j += 4) {
                int s0 = csr[j], s1 = csr[j + 1], s2 = csr[j + 2], s3 = csr[j + 3];
                float4 v0 = base[s0 * 32 + lane];
                float4 v1 = base[s1 * 32 + lane];
                float4 v2 = base[s2 * 32 + lane];
                float4 v3 = base[s3 * 32 + lane];
                ax += (v0.x + v1.x) + (v2.x + v3.x);
                ay += (v0.y + v1.y) + (v2.y + v3.y);
                az += (v0.z + v1.z) + (v2.z + v3.z);
                aw += (v0.w + v1.w) + (v2.w + v3.w);
            }
            for (; j < e1; ++j) {
                float4 v = base[csr[j] * 32 + lane];
                ax += v.x; ay += v.y; az += v.z; aw += v.w;
            }
        }
        unsigned short h0 = f2bf(ax), h1 = f2bf(ay), h2 = f2bf(az), h3 = f2bf(aw);
        unsigned short l0 = f2bf(ax - bf2f(h0)), l1 = f2bf(ay - bf2f(h1));
        unsigned short l2 = f2bf(az - bf2f(h2)), l3 = f2bf(aw - bf2f(h3));
        ushort4 ph = {h0, h1, h2, h3};
        ushort4 pl = {l0, l1, l2, l3};
        *(ushort4*)(&AhL[lrow][lane * 4]) = ph;
        *(ushort4*)(&AlL[lrow][lane * 4]) = pl;
    }
    __syncthreads();

    // ---- Phase B: MFMA, 8 waves = 8 col-groups over 64 rows ----
    const int lane64 = threadIdx.x & 63;
    const int wv = threadIdx.x >> 6;       // 0..7
    const int l15 = lane64 & 15;
    const int lg = lane64 >> 4;            // 0..3
    const int colbase = wv * 16;

    bf16x8 bh[4], bl[4];
#pragma unroll
    for (int ks = 0; ks < 4; ++ks) {
        int nn = colbase + l15;
        int k = ks * 32 + lg * 8;
        bh[ks] = *(const bf16x8*)(Bh + nn * 128 + k);
        bl[ks] = *(const bf16x8*)(Bl + nn * 128 + k);
    }
    float bias0 = bias[colbase + l15];
    float s0 = 0.f, q0 = 0.f;

#pragma unroll
    for (int mr = 0; mr < 4; ++mr) {
        int lrow = mr * 16 + l15;
        bf16x8 ah[4], al[4];
#pragma unroll
        for (int ks = 0; ks < 4; ++ks) {
            ah[ks] = *(const bf16x8*)(&AhL[lrow][ks * 32 + lg * 8]);
            al[ks] = *(const bf16x8*)(&AlL[lrow][ks * 32 + lg * 8]);
        }
        f32x4 acc = {0.f, 0.f, 0.f, 0.f};
#pragma unroll
        for (int ks = 0; ks < 4; ++ks) {
            acc = __builtin_amdgcn_mfma_f32_16x16x32_bf16(ah[ks], bh[ks], acc, 0, 0, 0);
            acc = __builtin_amdgcn_mfma_f32_16x16x32_bf16(ah[ks], bl[ks], acc, 0, 0, 0);
            acc = __builtin_amdgcn_mfma_f32_16x16x32_bf16(al[ks], bh[ks], acc, 0, 0, 0);
        }
        int orow0 = rowbase + mr * 16 + lg * 4;
#pragma unroll
        for (int r = 0; r < 4; ++r) {
            int orow = orow0 + r;
            if (orow < n) {
                float v0 = acc[r] + bias0;
                v0 = v0 > 0.f ? v0 : 0.2f * v0;
                int c0 = colbase + l15;
                unsigned short h0 = f2bf(v0);
                Ohi[orow * 128 + c0] = h0;
                Olo[orow * 128 + c0] = f2bf(v0 - bf2f(h0));
                s0 += v0; q0 += v0 * v0;
            }
        }
    }
    s0 += __shfl_xor(s0, 16); s0 += __shfl_xor(s0, 32);
    q0 += __shfl_xor(q0, 16); q0 += __shfl_xor(q0, 32);
    if (lg == 0) {
        atomicAdd(&colsum[colbase + l15], s0);
        atomicAdd(&colsq[colbase + l15], q0);
    }
}

// ------------------------------- GEMM-2 ------------------------------------
// 512 threads, 64-row tile, LDS-staged A (coalesced 16B copies of h1 hi/lo),
// then the same 8-wave split-bf16 MFMA; bias + leaky; fp32 out.

__launch_bounds__(512, 8)
__global__ void gemm2_split(const unsigned short* __restrict__ Ah, const unsigned short* __restrict__ Al,
                            const unsigned short* __restrict__ Bh, const unsigned short* __restrict__ Bl,
                            const float* __restrict__ bias, float* __restrict__ Of32,
                            int nrows) {
    __shared__ unsigned short AhL[64][APAD];
    __shared__ unsigned short AlL[64][APAD];

    const int rowbase = blockIdx.x * 64;

    // ---- Phase A: coalesced copy, 64 rows x 128 ushorts = 1024 x 8-ushort chunks
    int t = threadIdx.x;
#pragma unroll
    for (int c = 0; c < 2; ++c) {
        int chunk = c * 512 + t;
        int row = chunk >> 4;            // 0..63
        int seg = chunk & 15;            // 16B segment within row
        int gr = rowbase + row;
        int gsrc = (gr < nrows ? gr : nrows - 1) * 128 + seg * 8;
        *(uint4*)(&AhL[row][seg * 8]) = *(const uint4*)(Ah + gsrc);
        *(uint4*)(&AlL[row][seg * 8]) = *(const uint4*)(Al + gsrc);
    }
    __syncthreads();

    // ---- Phase B: MFMA, 8 waves = 8 col-groups over 64 rows ----
    const int lane64 = threadIdx.x & 63;
    const int wv = threadIdx.x >> 6;       // 0..7
    const int l15 = lane64 & 15;
    const int lg = lane64 >> 4;            // 0..3
    const int colbase = wv * 16;

    bf16x8 bh[4], bl[4];
#pragma unroll
    for (int ks = 0; ks < 4; ++ks) {
        int nn = colbase + l15;
        int k = ks * 32 + lg * 8;
        bh[ks] = *(const bf16x8*)(Bh + nn * 128 + k);
        bl[ks] = *(const bf16x8*)(Bl + nn * 128 + k);
    }
    float bias0 = bias[colbase + l15];

#pragma unroll
    for (int mr = 0; mr < 4; ++mr) {
        int lrow = mr * 16 + l15;
        bf16x8 ah[4], al[4];
#pragma unroll
        for (int ks = 0; ks < 4; ++ks) {
            ah[ks] = *(const bf16x8*)(&AhL[lrow][ks * 32 + lg * 8]);
            al[ks] = *(const bf16x8*)(&AlL[lrow][ks * 32 + lg * 8]);
        }
        f32x4 acc = {0.f, 0.f, 0.f, 0.f};
#pragma unroll
        for (int ks = 0; ks < 4; ++ks) {
            acc = __builtin_amdgcn_mfma_f32_16x16x32_bf16(ah[ks], bh[ks], acc, 0, 0, 0);
            acc = __builtin_amdgcn_mfma_f32_16x16x32_bf16(ah[ks], bl[ks], acc, 0, 0, 0);
            acc = __builtin_amdgcn_mfma_f32_16x16x32_bf16(al[ks], bh[ks], acc, 0, 0, 0);
        }
        int orow0 = rowbase + mr * 16 + lg * 4;
#pragma unroll
        for (int r = 0; r < 4; ++r) {
            int orow = orow0 + r;
            if (orow < nrows) {
                float v0 = acc[r] + bias0;
                v0 = v0 > 0.f ? v0 : 0.2f * v0;
                Of32[orow * 128 + colbase + l15] = v0;
            }
        }
    }
}

// ------------------------------ pooling -----------------------------------
// Block-per-graph: 512 blocks x 128 threads, thread-per-column, coalesced
// row reads; graph bounds via binary search over sorted batch[].

__global__ void pool_kernel(const float* __restrict__ h, const int* __restrict__ batch,
                            float* __restrict__ pooled, int n) {
    __shared__ int sb[2];
    int g = blockIdx.x;
    if (threadIdx.x < 2) {
        int target = g + threadIdx.x;     // lower_bound(batch, target)
        int lo = 0, hi = n;
        while (lo < hi) {
            int mid = (lo + hi) >> 1;
            if (batch[mid] < target) lo = mid + 1; else hi = mid;
        }
        sb[threadIdx.x] = lo;
    }
    __syncthreads();
    int i0 = sb[0], i1 = sb[1];
    int c = threadIdx.x;                  // 128 threads = 128 columns
    float acc = 0.f;
    for (int i = i0; i < i1; ++i) acc += h[(size_t)i * 128 + c];
    pooled[g * 128 + c] = acc;
}

__global__ void pool_stats(const float* __restrict__ pooled, const float* __restrict__ bn_g,
                           const float* __restrict__ bn_b, float* __restrict__ pscale,
                           float* __restrict__ pshift, int G) {
    __shared__ float ss[8][128], sq[8][128];
    int tid = threadIdx.x;           // 1024 threads
    int c = tid & 127, seg = tid >> 7;
    int per = (G + 7) / 8;
    int g0 = seg * per;
    int g1 = g0 + per; if (g1 > G) g1 = G;
    float s = 0.f, q = 0.f;
    for (int g = g0; g < g1; ++g) { float v = pooled[g * 128 + c]; s += v; q += v * v; }
    ss[seg][c] = s; sq[seg][c] = q;
    __syncthreads();
    if (seg == 0) {
        for (int t2 = 1; t2 < 8; ++t2) { s += ss[t2][c]; q += sq[t2][c]; }
        float mu = s / (float)G;
        float var = q / (float)G - mu * mu;
        float rs = rsqrtf(var + 1e-5f);
        float sc = rs * bn_g[c];
        pscale[c] = sc;
        pshift[c] = bn_b[c] - mu * sc;
    }
}

__global__ void final_fc(const float* __restrict__ pooled, const float* __restrict__ pscale,
                         const float* __restrict__ pshift, const float* __restrict__ fcW,
                         const float* __restrict__ fcb, float* __restrict__ out, int total) {
    int idx = blockIdx.x * 256 + threadIdx.x;
    if (idx >= total) return;
    int o = idx & 63, g = idx >> 6;
    float acc = fcb[o];
    const float* prow = pooled + g * 128;
#pragma unroll 4
    for (int c = 0; c < 128; ++c) {
        float z = prow[c] * pscale[c] + pshift[c];
        acc += z * fcW[c * 64 + o];
    }
    out[idx] = acc;
}

// ------------------------------ launcher ----------------------------------

extern "C" void kernel_launch(void* const* d_in, const int* in_sizes, int n_in,
                              void* d_out, int out_size, void* d_ws, size_t ws_size,
                              hipStream_t stream) {
    const float* x    = (const float*)d_in[0];
    const int*   ei   = (const int*)d_in[1];
    const int*   batch= (const int*)d_in[2];
    const float* W1s  = (const float*)d_in[3];
    const float* b1s  = (const float*)d_in[4];
    const float* g1s  = (const float*)d_in[5];
    const float* be1s = (const float*)d_in[6];
    const float* W2s  = (const float*)d_in[7];
    const float* b2s  = (const float*)d_in[8];
    const float* bn_g = (const float*)d_in[9];
    const float* bn_b = (const float*)d_in[10];
    const float* fcW  = (const float*)d_in[11];
    const float* fcb  = (const float*)d_in[12];
    float* out = (float*)d_out;

    const int N = in_sizes[0] / 128;
    const int E = in_sizes[1] / 2;
    const int G = out_size / 64;
    const int L = in_sizes[3] / (128 * 128);
    const int* src = ei;
    const int* dst = ei + E;

    size_t off = 0;
    auto carve = [&](size_t bytes) -> void* {
        void* p = (char*)d_ws + off;
        off += (bytes + 255) & ~(size_t)255;
        return p;
    };
    int* deg    = (int*)carve((size_t)N * 4);
    int* cur    = (int*)carve((size_t)N * 4);
    int* ofs    = (int*)carve((size_t)(N + 1) * 4);
    int* bsum   = (int*)carve(4096 * 4);
    int* csr    = (int*)carve((size_t)E * 4);
    unsigned short* h1H  = (unsigned short*)carve((size_t)N * 128 * 2);
    unsigned short* h1L  = (unsigned short*)carve((size_t)N * 128 * 2);
    float* hbuf  = (float*)carve((size_t)N * 128 * 4);
    unsigned short* wt1H = (unsigned short*)carve((size_t)L * 16384 * 2);
    unsigned short* wt1L = (unsigned short*)carve((size_t)L * 16384 * 2);
    unsigned short* wt2H = (unsigned short*)carve(16384 * 2);
    unsigned short* wt2L = (unsigned short*)carve(16384 * 2);
    float* b2p    = (float*)carve(128 * 4);
    float* colsum = (float*)carve((size_t)L * 128 * 4);
    float* colsq  = (float*)carve((size_t)L * 128 * 4);
    float* pooled = (float*)carve((size_t)G * 128 * 4);
    float* pscale = (float*)carve(128 * 4);
    float* pshift = (float*)carve(128 * 4);
    (void)ws_size; (void)n_in;

    // ---- weight prep for all layers + zero all stats ----
    int wtot = L * 16384;
    prep_w1_all<<<(wtot + 255) / 256, 256, 0, stream>>>(W1s, wt1H, wt1L,
                                                        colsum, colsq, wtot, L * 128);

    // ---- CSR build (once per call) ----
    zero2_kernel<<<(N + 255) / 256, 256, 0, stream>>>(deg, cur, N);
    hist_kernel<<<(E + 255) / 256, 256, 0, stream>>>(dst, deg, E);
    int nb1 = (N + 255) / 256;
    scan1_kernel<<<nb1, 256, 0, stream>>>(deg, ofs, bsum, N);
    scan2_kernel<<<1, 1024, 0, stream>>>(bsum, nb1);
    scan3_kernel<<<nb1, 256, 0, stream>>>(ofs, bsum, N, E);
    fill_kernel<<<(E + 255) / 256, 256, 0, stream>>>(src, dst, ofs, cur, csr, E);

    // ---- layers ----
    const float* hprev = x;
    int tileBlocks = (N + 63) / 64;
    for (int l = 0; l < L; ++l) {
        fused_agg_gemm1<<<tileBlocks, 512, 0, stream>>>(hprev, ofs, csr,
                                                        wt1H + l * 16384, wt1L + l * 16384,
                                                        b1s + l * 128,
                                                        h1H, h1L,
                                                        colsum + l * 128, colsq + l * 128, N);
        w2t_fold<<<64, 256, 0, stream>>>(W2s + (size_t)l * 16384, b2s + l * 128,
                                         g1s + l * 128, be1s + l * 128,
                                         colsum + l * 128, colsq + l * 128,
                                         wt2H, wt2L, b2p, N);
        gemm2_split<<<tileBlocks, 512, 0, stream>>>(h1H, h1L, wt2H, wt2L, b2p, hbuf, N);
        hprev = hbuf;
    }

    // ---- readout ----
    pool_kernel<<<G, 128, 0, stream>>>(hbuf, batch, pooled, N);
    pool_stats<<<1, 1024, 0, stream>>>(pooled, bn_g, bn_b, pscale, pshift, G);
    final_fc<<<(G * 64 + 255) / 256, 256, 0, stream>>>(pooled, pscale, pshift, fcW, fcb,
                                                       out, G * 64);
}

// Round 16
// 773.621 us; speedup vs baseline: 1.1360x; 1.1360x over previous
//
#include <hip/hip_runtime.h>

// ---------------------------------------------------------------------------
// GIN forward on MI355X.
//   f2h (x fp32 -> fp16 copy), prep_w1_all, CSR build
//   per layer: fused_agg_gemm1 (gather fp16 rows -> fp32 sum -> LDS bf16 hi/lo;
//              8 waves split-bf16 MFMA + bias+leaky+stats)
//              w2t_fold (BN fold + W2 transform + b2')
//              gemm2_split (LDS-staged A, split-bf16 MFMA -> fp16 hbuf)
//   pool (block-per-graph, fp16 in), pool_stats, final_fc
// ---------------------------------------------------------------------------

typedef __attribute__((ext_vector_type(8))) __bf16 bf16x8;
typedef __attribute__((ext_vector_type(4))) float  f32x4;
typedef __attribute__((ext_vector_type(4))) _Float16 f16x4;

__device__ __forceinline__ unsigned short f2bf(float f) {
    union { float f; unsigned int u; } v; v.f = f;
    unsigned int r = v.u + 0x7fffu + ((v.u >> 16) & 1u);
    return (unsigned short)(r >> 16);
}
__device__ __forceinline__ float bf2f(unsigned short h) {
    union { unsigned int u; float f; } v; v.u = ((unsigned int)h) << 16;
    return v.f;
}

// ------------------------------ fp32 -> fp16 -------------------------------

__global__ void f2h_kernel(const float* __restrict__ in, _Float16* __restrict__ out,
                           int total4) {           // total4 = N*128/4
    int i = blockIdx.x * 256 + threadIdx.x;
    if (i >= total4) return;
    float4 v = ((const float4*)in)[i];
    f16x4 o = {(_Float16)v.x, (_Float16)v.y, (_Float16)v.z, (_Float16)v.w};
    ((f16x4*)out)[i] = o;
}

// ------------------------------ CSR build ---------------------------------

__global__ void zero2_kernel(int* __restrict__ a, int* __restrict__ b, int n) {
    int i = blockIdx.x * 256 + threadIdx.x;
    if (i < n) { a[i] = 0; b[i] = 0; }
}

__global__ void hist_kernel(const int* __restrict__ dst, int* __restrict__ deg, int E) {
    int e = blockIdx.x * 256 + threadIdx.x;
    if (e < E) atomicAdd(&deg[dst[e]], 1);
}

__global__ void scan1_kernel(const int* __restrict__ deg, int* __restrict__ ofs,
                             int* __restrict__ bsum, int n) {
    __shared__ int sh[256];
    int tid = threadIdx.x;
    int i = blockIdx.x * 256 + tid;
    int v = (i < n) ? deg[i] : 0;
    sh[tid] = v;
    __syncthreads();
    for (int o = 1; o < 256; o <<= 1) {
        int tmp = (tid >= o) ? sh[tid - o] : 0;
        __syncthreads();
        sh[tid] += tmp;
        __syncthreads();
    }
    if (i < n) ofs[i] = sh[tid] - v;           // exclusive within block
    if (tid == 255) bsum[blockIdx.x] = sh[255];
}

__global__ void scan2_kernel(int* __restrict__ bsum, int nb) {
    __shared__ int sh[1024];
    int tid = threadIdx.x;
    int v = (tid < nb) ? bsum[tid] : 0;
    sh[tid] = v;
    __syncthreads();
    for (int o = 1; o < 1024; o <<= 1) {
        int tmp = (tid >= o) ? sh[tid - o] : 0;
        __syncthreads();
        sh[tid] += tmp;
        __syncthreads();
    }
    if (tid < nb) bsum[tid] = sh[tid] - v;     // exclusive
}

__global__ void scan3_kernel(int* __restrict__ ofs, const int* __restrict__ bsum,
                             int n, int Etot) {
    int i = blockIdx.x * 256 + threadIdx.x;
    if (i < n) ofs[i] += bsum[blockIdx.x];
    if (i == 0) ofs[n] = Etot;
}

__global__ void fill_kernel(const int* __restrict__ src, const int* __restrict__ dst,
                            const int* __restrict__ ofs, int* __restrict__ cur,
                            int* __restrict__ csr, int E) {
    int e = blockIdx.x * 256 + threadIdx.x;
    if (e >= E) return;
    int d = dst[e];
    int p = atomicAdd(&cur[d], 1);
    csr[ofs[d] + p] = src[e];
}

// --------------------------- weight prep ----------------------------------

__global__ void prep_w1_all(const float* __restrict__ W1s, unsigned short* __restrict__ Bth,
                            unsigned short* __restrict__ Btl,
                            float* __restrict__ colsum, float* __restrict__ colsq,
                            int total, int nstats) {
    int t = blockIdx.x * 256 + threadIdx.x;   // total = L*16384
    if (t < nstats) { colsum[t] = 0.f; colsq[t] = 0.f; }
    if (t >= total) return;
    int lbase = t & ~16383;                   // layer offset
    int r = t & 16383;
    int n = r >> 7, k = r & 127;
    float v = W1s[lbase + k * 128 + n];
    unsigned short h = f2bf(v);
    Bth[t] = h;
    Btl[t] = f2bf(v - bf2f(h));
}

// BN fold + W2 transform + b2' in one kernel (64 blocks).
__global__ void w2t_fold(const float* __restrict__ W2, const float* __restrict__ b2,
                         const float* __restrict__ g1, const float* __restrict__ be1,
                         const float* __restrict__ colsum, const float* __restrict__ colsq,
                         unsigned short* __restrict__ Bth, unsigned short* __restrict__ Btl,
                         float* __restrict__ b2p, int nrows) {
    __shared__ float s[128], tt[128];
    int tid = threadIdx.x;          // 256 threads
    if (tid < 128) {
        float mu = colsum[tid] / (float)nrows;
        float var = colsq[tid] / (float)nrows - mu * mu;
        float rs = rsqrtf(var + 1e-5f);
        float sc = rs * g1[tid];
        s[tid] = sc;
        tt[tid] = be1[tid] - mu * sc;
    }
    __syncthreads();
    int t = blockIdx.x * 256 + tid;           // 64 blocks * 256 = 16384
    int n = t >> 7, k = t & 127;
    float v = s[k] * W2[k * 128 + n];
    unsigned short h = f2bf(v);
    Bth[t] = h;
    Btl[t] = f2bf(v - bf2f(h));
    if (blockIdx.x == 0) {
        __shared__ float part[2][128];
        int nn = tid & 127, half = tid >> 7;
        float acc = 0.f;
        for (int kk = half * 64; kk < half * 64 + 64; ++kk)
            acc += tt[kk] * W2[kk * 128 + nn];
        part[half][nn] = acc;
        __syncthreads();
        if (tid < 128) b2p[tid] = b2[tid] + part[0][tid] + part[1][tid];
    }
}

// --------------------- fused aggregation + GEMM-1 --------------------------
// 512 threads, 64-node tile, 34.8 KB LDS, 4 blocks/CU.
// Phase A: 16 half-waves gather 4 nodes each; fp16 rows (256B), 8-deep pipeline;
//          fp32 accumulate; split to bf16 hi/lo in LDS.
// Phase B: 8 waves, one 16-col group each; split-bf16 MFMA; bias+leaky;
//          write h1 hi/lo + column stats.

#define APAD 136   // 128 + 8 bf16 pad: row stride 272B, 16B-aligned, 2-way banks

__launch_bounds__(512, 8)
__global__ void fused_agg_gemm1(const _Float16* __restrict__ h, const int* __restrict__ ofs,
                                const int* __restrict__ csr,
                                const unsigned short* __restrict__ Bh,
                                const unsigned short* __restrict__ Bl,
                                const float* __restrict__ bias,
                                unsigned short* __restrict__ Ohi,
                                unsigned short* __restrict__ Olo,
                                float* __restrict__ colsum, float* __restrict__ colsq,
                                int n) {
    __shared__ unsigned short AhL[64][APAD];
    __shared__ unsigned short AlL[64][APAD];

    const int rowbase = blockIdx.x * 64;
    const int hw = threadIdx.x >> 5;       // half-wave 0..15
    const int lane = threadIdx.x & 31;
    const f16x4* base = (const f16x4*)h;   // row = 32 x f16x4 (8B), lane -> cols lane*4..+3

    // ---- Phase A: gather 4 nodes per half-wave ----
    for (int i = 0; i < 4; ++i) {
        int lrow = hw * 4 + i;
        int node = rowbase + lrow;
        float ax = 0.f, ay = 0.f, az = 0.f, aw = 0.f;
        if (node < n) {
            f16x4 a = base[node * 32 + lane];
            ax = (float)a.x; ay = (float)a.y; az = (float)a.z; aw = (float)a.w;
            int e0 = ofs[node], e1 = ofs[node + 1];
            int j = e0;
            for (; j + 8 <= e1; j += 8) {
                int s[8];
#pragma unroll
                for (int u = 0; u < 8; ++u) s[u] = csr[j + u];
                f16x4 v[8];
#pragma unroll
                for (int u = 0; u < 8; ++u) v[u] = base[s[u] * 32 + lane];
#pragma unroll
                for (int u = 0; u < 8; ++u) {
                    ax += (float)v[u].x; ay += (float)v[u].y;
                    az += (float)v[u].z; aw += (float)v[u].w;
                }
            }
            for (; j + 4 <= e1; j += 4) {
                int s0 = csr[j], s1 = csr[j + 1], s2 = csr[j + 2], s3 = csr[j + 3];
                f16x4 v0 = base[s0 * 32 + lane];
                f16x4 v1 = base[s1 * 32 + lane];
                f16x4 v2 = base[s2 * 32 + lane];
                f16x4 v3 = base[s3 * 32 + lane];
                ax += ((float)v0.x + (float)v1.x) + ((float)v2.x + (float)v3.x);
                ay += ((float)v0.y + (float)v1.y) + ((float)v2.y + (float)v3.y);
                az += ((float)v0.z + (float)v1.z) + ((float)v2.z + (float)v3.z);
                aw += ((float)v0.w + (float)v1.w) + ((float)v2.w + (float)v3.w);
            }
            for (; j < e1; ++j) {
                f16x4 v = base[csr[j] * 32 + lane];
                ax += (float)v.x; ay += (float)v.y; az += (float)v.z; aw += (float)v.w;
            }
        }
        unsigned short h0 = f2bf(ax), h1 = f2bf(ay), h2 = f2bf(az), h3 = f2bf(aw);
        unsigned short l0 = f2bf(ax - bf2f(h0)), l1 = f2bf(ay - bf2f(h1));
        unsigned short l2 = f2bf(az - bf2f(h2)), l3 = f2bf(aw - bf2f(h3));
        ushort4 ph = {h0, h1, h2, h3};
        ushort4 pl = {l0, l1, l2, l3};
        *(ushort4*)(&AhL[lrow][lane * 4]) = ph;
        *(ushort4*)(&AlL[lrow][lane * 4]) = pl;
    }
    __syncthreads();

    // ---- Phase B: MFMA, 8 waves = 8 col-groups over 64 rows ----
    const int lane64 = threadIdx.x & 63;
    const int wv = threadIdx.x >> 6;       // 0..7
    const int l15 = lane64 & 15;
    const int lg = lane64 >> 4;            // 0..3
    const int colbase = wv * 16;

    bf16x8 bh[4], bl[4];
#pragma unroll
    for (int ks = 0; ks < 4; ++ks) {
        int nn = colbase + l15;
        int k = ks * 32 + lg * 8;
        bh[ks] = *(const bf16x8*)(Bh + nn * 128 + k);
        bl[ks] = *(const bf16x8*)(Bl + nn * 128 + k);
    }
    float bias0 = bias[colbase + l15];
    float s0 = 0.f, q0 = 0.f;

#pragma unroll
    for (int mr = 0; mr < 4; ++mr) {
        int lrow = mr * 16 + l15;
        bf16x8 ah[4], al[4];
#pragma unroll
        for (int ks = 0; ks < 4; ++ks) {
            ah[ks] = *(const bf16x8*)(&AhL[lrow][ks * 32 + lg * 8]);
            al[ks] = *(const bf16x8*)(&AlL[lrow][ks * 32 + lg * 8]);
        }
        f32x4 acc = {0.f, 0.f, 0.f, 0.f};
#pragma unroll
        for (int ks = 0; ks < 4; ++ks) {
            acc = __builtin_amdgcn_mfma_f32_16x16x32_bf16(ah[ks], bh[ks], acc, 0, 0, 0);
            acc = __builtin_amdgcn_mfma_f32_16x16x32_bf16(ah[ks], bl[ks], acc, 0, 0, 0);
            acc = __builtin_amdgcn_mfma_f32_16x16x32_bf16(al[ks], bh[ks], acc, 0, 0, 0);
        }
        int orow0 = rowbase + mr * 16 + lg * 4;
#pragma unroll
        for (int r = 0; r < 4; ++r) {
            int orow = orow0 + r;
            if (orow < n) {
                float v0 = acc[r] + bias0;
                v0 = v0 > 0.f ? v0 : 0.2f * v0;
                int c0 = colbase + l15;
                unsigned short h0 = f2bf(v0);
                Ohi[orow * 128 + c0] = h0;
                Olo[orow * 128 + c0] = f2bf(v0 - bf2f(h0));
                s0 += v0; q0 += v0 * v0;
            }
        }
    }
    s0 += __shfl_xor(s0, 16); s0 += __shfl_xor(s0, 32);
    q0 += __shfl_xor(q0, 16); q0 += __shfl_xor(q0, 32);
    if (lg == 0) {
        atomicAdd(&colsum[colbase + l15], s0);
        atomicAdd(&colsq[colbase + l15], q0);
    }
}

// ------------------------------- GEMM-2 ------------------------------------
// 512 threads, 64-row tile, LDS-staged A (coalesced 16B copies of h1 hi/lo),
// then the same 8-wave split-bf16 MFMA; bias + leaky; fp16 out.

__launch_bounds__(512, 8)
__global__ void gemm2_split(const unsigned short* __restrict__ Ah, const unsigned short* __restrict__ Al,
                            const unsigned short* __restrict__ Bh, const unsigned short* __restrict__ Bl,
                            const float* __restrict__ bias, _Float16* __restrict__ Oh16,
                            int nrows) {
    __shared__ unsigned short AhL[64][APAD];
    __shared__ unsigned short AlL[64][APAD];

    const int rowbase = blockIdx.x * 64;

    // ---- Phase A: coalesced copy, 64 rows x 128 ushorts = 1024 x 8-ushort chunks
    int t = threadIdx.x;
#pragma unroll
    for (int c = 0; c < 2; ++c) {
        int chunk = c * 512 + t;
        int row = chunk >> 4;            // 0..63
        int seg = chunk & 15;            // 16B segment within row
        int gr = rowbase + row;
        int gsrc = (gr < nrows ? gr : nrows - 1) * 128 + seg * 8;
        *(uint4*)(&AhL[row][seg * 8]) = *(const uint4*)(Ah + gsrc);
        *(uint4*)(&AlL[row][seg * 8]) = *(const uint4*)(Al + gsrc);
    }
    __syncthreads();

    // ---- Phase B: MFMA, 8 waves = 8 col-groups over 64 rows ----
    const int lane64 = threadIdx.x & 63;
    const int wv = threadIdx.x >> 6;       // 0..7
    const int l15 = lane64 & 15;
    const int lg = lane64 >> 4;            // 0..3
    const int colbase = wv * 16;

    bf16x8 bh[4], bl[4];
#pragma unroll
    for (int ks = 0; ks < 4; ++ks) {
        int nn = colbase + l15;
        int k = ks * 32 + lg * 8;
        bh[ks] = *(const bf16x8*)(Bh + nn * 128 + k);
        bl[ks] = *(const bf16x8*)(Bl + nn * 128 + k);
    }
    float bias0 = bias[colbase + l15];

#pragma unroll
    for (int mr = 0; mr < 4; ++mr) {
        int lrow = mr * 16 + l15;
        bf16x8 ah[4], al[4];
#pragma unroll
        for (int ks = 0; ks < 4; ++ks) {
            ah[ks] = *(const bf16x8*)(&AhL[lrow][ks * 32 + lg * 8]);
            al[ks] = *(const bf16x8*)(&AlL[lrow][ks * 32 + lg * 8]);
        }
        f32x4 acc = {0.f, 0.f, 0.f, 0.f};
#pragma unroll
        for (int ks = 0; ks < 4; ++ks) {
            acc = __builtin_amdgcn_mfma_f32_16x16x32_bf16(ah[ks], bh[ks], acc, 0, 0, 0);
            acc = __builtin_amdgcn_mfma_f32_16x16x32_bf16(ah[ks], bl[ks], acc, 0, 0, 0);
            acc = __builtin_amdgcn_mfma_f32_16x16x32_bf16(al[ks], bh[ks], acc, 0, 0, 0);
        }
        int orow0 = rowbase + mr * 16 + lg * 4;
#pragma unroll
        for (int r = 0; r < 4; ++r) {
            int orow = orow0 + r;
            if (orow < nrows) {
                float v0 = acc[r] + bias0;
                v0 = v0 > 0.f ? v0 : 0.2f * v0;
                Oh16[orow * 128 + colbase + l15] = (_Float16)v0;
            }
        }
    }
}

// ------------------------------ pooling -----------------------------------
// Block-per-graph: 512 blocks x 128 threads, thread-per-column, coalesced
// fp16 row reads; graph bounds via binary search over sorted batch[].

__global__ void pool_kernel(const _Float16* __restrict__ h, const int* __restrict__ batch,
                            float* __restrict__ pooled, int n) {
    __shared__ int sb[2];
    int g = blockIdx.x;
    if (threadIdx.x < 2) {
        int target = g + threadIdx.x;     // lower_bound(batch, target)
        int lo = 0, hi = n;
        while (lo < hi) {
            int mid = (lo + hi) >> 1;
            if (batch[mid] < target) lo = mid + 1; else hi = mid;
        }
        sb[threadIdx.x] = lo;
    }
    __syncthreads();
    int i0 = sb[0], i1 = sb[1];
    int c = threadIdx.x;                  // 128 threads = 128 columns
    float acc = 0.f;
    for (int i = i0; i < i1; ++i) acc += (float)h[(size_t)i * 128 + c];
    pooled[g * 128 + c] = acc;
}

__global__ void pool_stats(const float* __restrict__ pooled, const float* __restrict__ bn_g,
                           const float* __restrict__ bn_b, float* __restrict__ pscale,
                           float* __restrict__ pshift, int G) {
    __shared__ float ss[8][128], sq[8][128];
    int tid = threadIdx.x;           // 1024 threads
    int c = tid & 127, seg = tid >> 7;
    int per = (G + 7) / 8;
    int g0 = seg * per;
    int g1 = g0 + per; if (g1 > G) g1 = G;
    float s = 0.f, q = 0.f;
    for (int g = g0; g < g1; ++g) { float v = pooled[g * 128 + c]; s += v; q += v * v; }
    ss[seg][c] = s; sq[seg][c] = q;
    __syncthreads();
    if (seg == 0) {
        for (int t2 = 1; t2 < 8; ++t2) { s += ss[t2][c]; q += sq[t2][c]; }
        float mu = s / (float)G;
        float var = q / (float)G - mu * mu;
        float rs = rsqrtf(var + 1e-5f);
        float sc = rs * bn_g[c];
        pscale[c] = sc;
        pshift[c] = bn_b[c] - mu * sc;
    }
}

__global__ void final_fc(const float* __restrict__ pooled, const float* __restrict__ pscale,
                         const float* __restrict__ pshift, const float* __restrict__ fcW,
                         const float* __restrict__ fcb, float* __restrict__ out, int total) {
    int idx = blockIdx.x * 256 + threadIdx.x;
    if (idx >= total) return;
    int o = idx & 63, g = idx >> 6;
    float acc = fcb[o];
    const float* prow = pooled + g * 128;
#pragma unroll 4
    for (int c = 0; c < 128; ++c) {
        float z = prow[c] * pscale[c] + pshift[c];
        acc += z * fcW[c * 64 + o];
    }
    out[idx] = acc;
}

// ------------------------------ launcher ----------------------------------

extern "C" void kernel_launch(void* const* d_in, const int* in_sizes, int n_in,
                              void* d_out, int out_size, void* d_ws, size_t ws_size,
                              hipStream_t stream) {
    const float* x    = (const float*)d_in[0];
    const int*   ei   = (const int*)d_in[1];
    const int*   batch= (const int*)d_in[2];
    const float* W1s  = (const float*)d_in[3];
    const float* b1s  = (const float*)d_in[4];
    const float* g1s  = (const float*)d_in[5];
    const float* be1s = (const float*)d_in[6];
    const float* W2s  = (const float*)d_in[7];
    const float* b2s  = (const float*)d_in[8];
    const float* bn_g = (const float*)d_in[9];
    const float* bn_b = (const float*)d_in[10];
    const float* fcW  = (const float*)d_in[11];
    const float* fcb  = (const float*)d_in[12];
    float* out = (float*)d_out;

    const int N = in_sizes[0] / 128;
    const int E = in_sizes[1] / 2;
    const int G = out_size / 64;
    const int L = in_sizes[3] / (128 * 128);
    const int* src = ei;
    const int* dst = ei + E;

    size_t off = 0;
    auto carve = [&](size_t bytes) -> void* {
        void* p = (char*)d_ws + off;
        off += (bytes + 255) & ~(size_t)255;
        return p;
    };
    int* deg    = (int*)carve((size_t)N * 4);
    int* cur    = (int*)carve((size_t)N * 4);
    int* ofs    = (int*)carve((size_t)(N + 1) * 4);
    int* bsum   = (int*)carve(4096 * 4);
    int* csr    = (int*)carve((size_t)E * 4);
    unsigned short* h1H  = (unsigned short*)carve((size_t)N * 128 * 2);
    unsigned short* h1L  = (unsigned short*)carve((size_t)N * 128 * 2);
    _Float16* xh   = (_Float16*)carve((size_t)N * 128 * 2);
    _Float16* hb16 = (_Float16*)carve((size_t)N * 128 * 2);
    unsigned short* wt1H = (unsigned short*)carve((size_t)L * 16384 * 2);
    unsigned short* wt1L = (unsigned short*)carve((size_t)L * 16384 * 2);
    unsigned short* wt2H = (unsigned short*)carve(16384 * 2);
    unsigned short* wt2L = (unsigned short*)carve(16384 * 2);
    float* b2p    = (float*)carve(128 * 4);
    float* colsum = (float*)carve((size_t)L * 128 * 4);
    float* colsq  = (float*)carve((size_t)L * 128 * 4);
    float* pooled = (float*)carve((size_t)G * 128 * 4);
    float* pscale = (float*)carve(128 * 4);
    float* pshift = (float*)carve(128 * 4);
    (void)ws_size; (void)n_in;

    // ---- x -> fp16 copy + weight prep + zero stats ----
    int total4 = N * 32;    // N*128/4
    f2h_kernel<<<(total4 + 255) / 256, 256, 0, stream>>>(x, xh, total4);
    int wtot = L * 16384;
    prep_w1_all<<<(wtot + 255) / 256, 256, 0, stream>>>(W1s, wt1H, wt1L,
                                                        colsum, colsq, wtot, L * 128);

    // ---- CSR build (once per call) ----
    zero2_kernel<<<(N + 255) / 256, 256, 0, stream>>>(deg, cur, N);
    hist_kernel<<<(E + 255) / 256, 256, 0, stream>>>(dst, deg, E);
    int nb1 = (N + 255) / 256;
    scan1_kernel<<<nb1, 256, 0, stream>>>(deg, ofs, bsum, N);
    scan2_kernel<<<1, 1024, 0, stream>>>(bsum, nb1);
    scan3_kernel<<<nb1, 256, 0, stream>>>(ofs, bsum, N, E);
    fill_kernel<<<(E + 255) / 256, 256, 0, stream>>>(src, dst, ofs, cur, csr, E);

    // ---- layers ----
    const _Float16* hprev = xh;
    int tileBlocks = (N + 63) / 64;
    for (int l = 0; l < L; ++l) {
        fused_agg_gemm1<<<tileBlocks, 512, 0, stream>>>(hprev, ofs, csr,
                                                        wt1H + l * 16384, wt1L + l * 16384,
                                                        b1s + l * 128,
                                                        h1H, h1L,
                                                        colsum + l * 128, colsq + l * 128, N);
        w2t_fold<<<64, 256, 0, stream>>>(W2s + (size_t)l * 16384, b2s + l * 128,
                                         g1s + l * 128, be1s + l * 128,
                                         colsum + l * 128, colsq + l * 128,
                                         wt2H, wt2L, b2p, N);
        gemm2_split<<<tileBlocks, 512, 0, stream>>>(h1H, h1L, wt2H, wt2L, b2p, hb16, N);
        hprev = hb16;
    }

    // ---- readout ----
    pool_kernel<<<G, 128, 0, stream>>>(hb16, batch, pooled, N);
    pool_stats<<<1, 1024, 0, stream>>>(pooled, bn_g, bn_b, pscale, pshift, G);
    final_fc<<<(G * 64 + 255) / 256, 256, 0, stream>>>(pooled, pscale, pshift, fcW, fcb,
                                                       out, G * 64);
}